// Round 1
// baseline (237.303 us; speedup 1.0000x reference)
//
#include <hip/hip_runtime.h>

typedef unsigned short u16;
typedef u16 u16x8 __attribute__((ext_vector_type(8)));
typedef u16 u16x4 __attribute__((ext_vector_type(4)));
typedef __bf16 bf8 __attribute__((ext_vector_type(8)));
typedef float f32x4 __attribute__((ext_vector_type(4)));

__device__ __forceinline__ u16 f2b(float f) {
  unsigned u = __float_as_uint(f);
  u += 0x7FFFu + ((u >> 16) & 1u);   // RNE
  return (u16)(u >> 16);
}
__device__ __forceinline__ float b2f(u16 h) {
  return __uint_as_float(((unsigned)h) << 16);
}
__device__ __forceinline__ bf8 asbf8(u16x8 v) {
  return __builtin_bit_cast(bf8, v);
}

// ---------------- prep kernels ----------------

__global__ __launch_bounds__(256) void xconv(const float* __restrict__ x,
                                             u16* __restrict__ xb) {
  int i = (blockIdx.x * 256 + threadIdx.x) * 4;
  float4 v = *(const float4*)(x + i);
  u16x4 o;
  o[0] = f2b(v.x); o[1] = f2b(v.y); o[2] = f2b(v.z); o[3] = f2b(v.w);
  *(u16x4*)(xb + i) = o;
}

// in [K][N] f32  ->  out [N][K] bf16   (transpose + convert)
__global__ __launch_bounds__(256) void wtrans(const float* __restrict__ in,
                                              u16* __restrict__ out,
                                              int N, int K) {
  __shared__ float tile[32][33];
  int tx = threadIdx.x & 31, ty = threadIdx.x >> 5;
  int n0 = blockIdx.x * 32, k0 = blockIdx.y * 32;
#pragma unroll
  for (int yy = 0; yy < 32; yy += 8)
    tile[ty + yy][tx] = in[(size_t)(k0 + ty + yy) * N + n0 + tx];
  __syncthreads();
#pragma unroll
  for (int yy = 0; yy < 32; yy += 8)
    out[(size_t)(n0 + ty + yy) * K + k0 + tx] = f2b(tile[tx][ty + yy]);
}

// RoPE in-place on q (cols 0..2047) and k (cols 2048..2559) of qkv [2048][3072]
__global__ __launch_bounds__(256) void rope_k(u16* __restrict__ qkv,
                                              const float* __restrict__ cs,
                                              const float* __restrict__ sn) {
  int idx = blockIdx.x * 256 + threadIdx.x;  // 2048*40*32
  int dp = idx & 31;
  int hh = (idx >> 5) % 40;
  int s  = idx / 1280;
  int col = (hh < 32) ? (hh * 64 + dp) : (2048 + (hh - 32) * 64 + dp);
  u16* p = qkv + (size_t)s * 3072 + col;
  float v1 = b2f(p[0]), v2 = b2f(p[32]);
  float c1 = cs[s * 64 + dp],      s1 = sn[s * 64 + dp];
  float c2 = cs[s * 64 + dp + 32], s2 = sn[s * 64 + dp + 32];
  p[0]  = f2b(v1 * c1 - v2 * s1);
  p[32] = f2b(v2 * c2 + v1 * s2);
}

// Vt[kh][d][s] = qkv[s][2560 + kh*64 + d]
__global__ __launch_bounds__(256) void vtrans(const u16* __restrict__ qkv,
                                              u16* __restrict__ Vt) {
  int idx = blockIdx.x * 256 + threadIdx.x;  // 8*64*2048 = 1<<20
  int s  = idx & 2047;
  int d  = (idx >> 11) & 63;
  int kh = idx >> 17;
  Vt[idx] = qkv[(size_t)s * 3072 + 2560 + kh * 64 + d];
}

// ---------------- GEMM: C[M][N] = A[M][K] * Bt[N][K]^T ----------------
// 128x128 tile, BK=32, 4 waves (2x2 of 64x64), 16x16x32 bf16 MFMA.
#define LDT 40  // padded LDS row (elems): 80B, 16B-aligned, even bank spread

__global__ __launch_bounds__(256) void gemm_bt(const u16* __restrict__ A,
                                               const u16* __restrict__ Bt,
                                               void* __restrict__ Cout,
                                               int M, int N, int K, int obf16) {
  __shared__ u16 As[128 * LDT];
  __shared__ u16 Bs[128 * LDT];
  const int t = threadIdx.x;
  const int lane = t & 63, wid = t >> 6;
  const int wm = (wid >> 1) * 64, wn = (wid & 1) * 64;
  const int la = lane & 15, lg = lane >> 4;
  const int m0 = blockIdx.y * 128, n0 = blockIdx.x * 128;
  const int arow = t >> 1, acol = (t & 1) * 16;

  const u16* Ap = A + (size_t)(m0 + arow) * K + acol;
  const u16* Bp = Bt + (size_t)(n0 + arow) * K + acol;
  u16* Asw = &As[arow * LDT + acol];
  u16* Bsw = &Bs[arow * LDT + acol];

  f32x4 acc[4][4] = {};

  for (int k0 = 0; k0 < K; k0 += 32) {
    __syncthreads();
    *(uint4*)Asw       = *(const uint4*)(Ap + k0);
    *(uint4*)(Asw + 8) = *(const uint4*)(Ap + k0 + 8);
    *(uint4*)Bsw       = *(const uint4*)(Bp + k0);
    *(uint4*)(Bsw + 8) = *(const uint4*)(Bp + k0 + 8);
    __syncthreads();
    bf8 af[4], bfr[4];
#pragma unroll
    for (int i = 0; i < 4; ++i)
      af[i] = asbf8(*(const u16x8*)(&As[(wm + i * 16 + la) * LDT + lg * 8]));
#pragma unroll
    for (int j = 0; j < 4; ++j)
      bfr[j] = asbf8(*(const u16x8*)(&Bs[(wn + j * 16 + la) * LDT + lg * 8]));
#pragma unroll
    for (int i = 0; i < 4; ++i)
#pragma unroll
      for (int j = 0; j < 4; ++j)
        acc[i][j] = __builtin_amdgcn_mfma_f32_16x16x32_bf16(af[i], bfr[j],
                                                            acc[i][j], 0, 0, 0);
  }

#pragma unroll
  for (int i = 0; i < 4; ++i)
#pragma unroll
    for (int j = 0; j < 4; ++j)
#pragma unroll
      for (int r = 0; r < 4; ++r) {
        int row = m0 + wm + i * 16 + lg * 4 + r;
        int col = n0 + wn + j * 16 + la;
        if (obf16) ((u16*)Cout)[(size_t)row * N + col] = f2b(acc[i][j][r]);
        else       ((float*)Cout)[(size_t)row * N + col] = acc[i][j][r];
      }
}

// ---------------- flash attention ----------------
// block = (head h, q-tile of 64). 4 waves x 16 q-rows. KV tiles of 64, causal.
__global__ __launch_bounds__(256) void attn_fwd(const u16* __restrict__ qkv,
                                                const u16* __restrict__ Vt,
                                                u16* __restrict__ aout) {
  const int h  = blockIdx.x;
  const int q0 = blockIdx.y * 64;
  const int kh = h >> 2;  // GROUPS = 4
  __shared__ u16 Ks[64 * 72];        // K[kv][d], padded
  __shared__ u16 Vs[64 * 72];        // V^T[d][kv], padded
  __shared__ u16 Ps[4 * 16 * 72];    // per-wave P[row][kv], padded
  const int t = threadIdx.x, lane = t & 63, w = t >> 6;
  const int la = lane & 15, lg = lane >> 4;

  // Q fragments (A operand), prescaled by 1/8 (exact)
  bf8 aq[2];
  {
    const int qrow = q0 + w * 16 + la;
#pragma unroll
    for (int kk = 0; kk < 2; ++kk) {
      u16x8 v = *(const u16x8*)(qkv + (size_t)qrow * 3072 + h * 64 + kk * 32 + lg * 8);
      u16x8 sv;
#pragma unroll
      for (int e = 0; e < 8; ++e) sv[e] = f2b(b2f(v[e]) * 0.125f);
      aq[kk] = asbf8(sv);
    }
  }

  float m_run[4], l_run[4];
  f32x4 oacc[4] = {};
#pragma unroll
  for (int r = 0; r < 4; ++r) { m_run[r] = -1e30f; l_run[r] = 0.f; }

  const int srow = t >> 2, scol = (t & 3) * 16;

  for (int j0 = 0; j0 <= q0; j0 += 64) {
    __syncthreads();
    {
      const u16* kp = qkv + (size_t)(j0 + srow) * 3072 + 2048 + kh * 64 + scol;
      *(uint4*)(&Ks[srow * 72 + scol])     = *(const uint4*)kp;
      *(uint4*)(&Ks[srow * 72 + scol + 8]) = *(const uint4*)(kp + 8);
      const u16* vp = Vt + (size_t)(kh * 64 + srow) * 2048 + j0 + scol;
      *(uint4*)(&Vs[srow * 72 + scol])     = *(const uint4*)vp;
      *(uint4*)(&Vs[srow * 72 + scol + 8]) = *(const uint4*)(vp + 8);
    }
    __syncthreads();

    // S = (Q/8) K^T
    f32x4 sacc[4] = {};
#pragma unroll
    for (int j = 0; j < 4; ++j)
#pragma unroll
      for (int kk = 0; kk < 2; ++kk) {
        bf8 bk = asbf8(*(const u16x8*)(&Ks[(j * 16 + la) * 72 + kk * 32 + lg * 8]));
        sacc[j] = __builtin_amdgcn_mfma_f32_16x16x32_bf16(aq[kk], bk, sacc[j], 0, 0, 0);
      }

    if (j0 == q0) {  // diagonal tile: causal mask
#pragma unroll
      for (int j = 0; j < 4; ++j)
#pragma unroll
        for (int r = 0; r < 4; ++r)
          if (j * 16 + la > w * 16 + lg * 4 + r) sacc[j][r] = -1e30f;
    }

    // online softmax (rows live in 16-lane groups)
#pragma unroll
    for (int r = 0; r < 4; ++r) {
      float mx = fmaxf(fmaxf(sacc[0][r], sacc[1][r]), fmaxf(sacc[2][r], sacc[3][r]));
      mx = fmaxf(mx, __shfl_xor(mx, 1));
      mx = fmaxf(mx, __shfl_xor(mx, 2));
      mx = fmaxf(mx, __shfl_xor(mx, 4));
      mx = fmaxf(mx, __shfl_xor(mx, 8));
      float m_new = fmaxf(m_run[r], mx);
      float sc = __expf(m_run[r] - m_new);
      m_run[r] = m_new;
      float rs = 0.f;
#pragma unroll
      for (int j = 0; j < 4; ++j) {
        float p = __expf(sacc[j][r] - m_new);
        sacc[j][r] = p;
        rs += p;
      }
      rs += __shfl_xor(rs, 1);
      rs += __shfl_xor(rs, 2);
      rs += __shfl_xor(rs, 4);
      rs += __shfl_xor(rs, 8);
      l_run[r] = l_run[r] * sc + rs;
#pragma unroll
      for (int jd = 0; jd < 4; ++jd) oacc[jd][r] *= sc;
    }

    // P -> LDS (re-layout C-frag -> A-frag), wave-private region
#pragma unroll
    for (int j = 0; j < 4; ++j)
#pragma unroll
      for (int r = 0; r < 4; ++r)
        Ps[w * 1152 + (lg * 4 + r) * 72 + j * 16 + la] = f2b(sacc[j][r]);

    bf8 pa[2];
#pragma unroll
    for (int kk = 0; kk < 2; ++kk)
      pa[kk] = asbf8(*(const u16x8*)(&Ps[w * 1152 + la * 72 + kk * 32 + lg * 8]));
#pragma unroll
    for (int jd = 0; jd < 4; ++jd)
#pragma unroll
      for (int kk = 0; kk < 2; ++kk) {
        bf8 vb = asbf8(*(const u16x8*)(&Vs[(jd * 16 + la) * 72 + kk * 32 + lg * 8]));
        oacc[jd] = __builtin_amdgcn_mfma_f32_16x16x32_bf16(pa[kk], vb, oacc[jd], 0, 0, 0);
      }
  }

#pragma unroll
  for (int jd = 0; jd < 4; ++jd)
#pragma unroll
    for (int r = 0; r < 4; ++r) {
      int row = q0 + w * 16 + lg * 4 + r;
      int col = h * 64 + jd * 16 + la;
      aout[(size_t)row * 2048 + col] = f2b(oacc[jd][r] / l_run[r]);
    }
}

// ---------------- launch ----------------

extern "C" void kernel_launch(void* const* d_in, const int* in_sizes, int n_in,
                              void* d_out, int out_size, void* d_ws, size_t ws_size,
                              hipStream_t stream) {
  (void)in_sizes; (void)n_in; (void)out_size; (void)ws_size;
  const float* x  = (const float*)d_in[0];
  const float* wq = (const float*)d_in[1];
  const float* wk = (const float*)d_in[2];
  const float* wv = (const float*)d_in[3];
  const float* wo = (const float*)d_in[4];
  const float* cs = (const float*)d_in[5];
  const float* sn = (const float*)d_in[6];
  // d_in[7] = causal mask, implemented analytically

  u16* ws    = (u16*)d_ws;
  u16* xb    = ws;                               // [2048][2048]  (later reused as aout)
  u16* wqkvT = ws + 4194304;                     // [3072][2048]  (later reused for Vt)
  u16* qkv   = ws + 4194304 + 6291456;           // [2048][3072]
  u16* woT   = ws + 4194304 + 6291456 * 2;       // [2048][2048]
  u16* Vt    = wqkvT;                            // [8][64][2048] after G1 is done
  u16* aout  = xb;                               // after G1 is done

  xconv<<<4096, 256, 0, stream>>>(x, xb);
  wtrans<<<dim3(64, 64), 256, 0, stream>>>(wq, wqkvT, 2048, 2048);
  wtrans<<<dim3(16, 64), 256, 0, stream>>>(wk, wqkvT + (size_t)2048 * 2048, 512, 2048);
  wtrans<<<dim3(16, 64), 256, 0, stream>>>(wv, wqkvT + (size_t)2560 * 2048, 512, 2048);
  wtrans<<<dim3(64, 64), 256, 0, stream>>>(wo, woT, 2048, 2048);

  gemm_bt<<<dim3(24, 16), 256, 0, stream>>>(xb, wqkvT, qkv, 2048, 3072, 2048, 1);
  rope_k<<<10240, 256, 0, stream>>>(qkv, cs, sn);
  vtrans<<<4096, 256, 0, stream>>>(qkv, Vt);
  attn_fwd<<<dim3(32, 32), 256, 0, stream>>>(qkv, Vt, aout);
  gemm_bt<<<dim3(16, 16), 256, 0, stream>>>(aout, woT, d_out, 2048, 2048, 2048, 0);
}

// Round 2
// 218.349 us; speedup vs baseline: 1.0868x; 1.0868x over previous
//
#include <hip/hip_runtime.h>

typedef unsigned short u16;
typedef u16 u16x8 __attribute__((ext_vector_type(8)));
typedef u16 u16x4 __attribute__((ext_vector_type(4)));
typedef __bf16 bf8 __attribute__((ext_vector_type(8)));
typedef float f32x4 __attribute__((ext_vector_type(4)));

__device__ __forceinline__ u16 f2b(float f) {
  unsigned u = __float_as_uint(f);
  u += 0x7FFFu + ((u >> 16) & 1u);   // RNE
  return (u16)(u >> 16);
}
__device__ __forceinline__ float b2f(u16 h) {
  return __uint_as_float(((unsigned)h) << 16);
}
__device__ __forceinline__ bf8 asbf8(u16x8 v) {
  return __builtin_bit_cast(bf8, v);
}
// async global->LDS, 16B per lane; l must be wave-uniform base (HW adds lane*16)
__device__ __forceinline__ void gll16(const u16* g, u16* l) {
  __builtin_amdgcn_global_load_lds(
      (const __attribute__((address_space(1))) unsigned*)(g),
      (__attribute__((address_space(3))) unsigned*)(l), 16, 0, 0);
}

// ---------------- prep kernels ----------------

__global__ __launch_bounds__(256) void xconv(const float* __restrict__ x,
                                             u16* __restrict__ xb) {
  int i = (blockIdx.x * 256 + threadIdx.x) * 4;
  float4 v = *(const float4*)(x + i);
  u16x4 o;
  o[0] = f2b(v.x); o[1] = f2b(v.y); o[2] = f2b(v.z); o[3] = f2b(v.w);
  *(u16x4*)(xb + i) = o;
}

// in [K][N] f32  ->  out [N][K] bf16   (transpose + convert)
__global__ __launch_bounds__(256) void wtrans(const float* __restrict__ in,
                                              u16* __restrict__ out,
                                              int N, int K) {
  __shared__ float tile[32][33];
  int tx = threadIdx.x & 31, ty = threadIdx.x >> 5;
  int n0 = blockIdx.x * 32, k0 = blockIdx.y * 32;
#pragma unroll
  for (int yy = 0; yy < 32; yy += 8)
    tile[ty + yy][tx] = in[(size_t)(k0 + ty + yy) * N + n0 + tx];
  __syncthreads();
#pragma unroll
  for (int yy = 0; yy < 32; yy += 8)
    out[(size_t)(n0 + ty + yy) * K + k0 + tx] = f2b(tile[tx][ty + yy]);
}

// RoPE in-place on q (cols 0..2047) and k (cols 2048..2559) of qkv [2048][3072]
__global__ __launch_bounds__(256) void rope_k(u16* __restrict__ qkv,
                                              const float* __restrict__ cs,
                                              const float* __restrict__ sn) {
  int idx = blockIdx.x * 256 + threadIdx.x;  // 2048*40*32
  int dp = idx & 31;
  int hh = (idx >> 5) % 40;
  int s  = idx / 1280;
  int col = (hh < 32) ? (hh * 64 + dp) : (2048 + (hh - 32) * 64 + dp);
  u16* p = qkv + (size_t)s * 3072 + col;
  float v1 = b2f(p[0]), v2 = b2f(p[32]);
  float c1 = cs[s * 64 + dp],      s1 = sn[s * 64 + dp];
  float c2 = cs[s * 64 + dp + 32], s2 = sn[s * 64 + dp + 32];
  p[0]  = f2b(v1 * c1 - v2 * s1);
  p[32] = f2b(v2 * c2 + v1 * s2);
}

// Vt[kh][d][s] = qkv[s][2560 + kh*64 + d]
__global__ __launch_bounds__(256) void vtrans(const u16* __restrict__ qkv,
                                              u16* __restrict__ Vt) {
  int idx = blockIdx.x * 256 + threadIdx.x;  // 8*64*2048 = 1<<20
  int s  = idx & 2047;
  int d  = (idx >> 11) & 63;
  int kh = idx >> 17;
  Vt[idx] = qkv[(size_t)s * 3072 + 2560 + kh * 64 + d];
}

// ---------------- GEMM: C[M][N] = A[M][K] * Bt[N][K]^T ----------------
// m97 structure: 128x128 tile, BK=32, 4 waves (2x2 of 64x64), linear LDS,
// global_load_lds width=16, 2 barriers per K-step.

__global__ __launch_bounds__(256) void gemm_bt(const u16* __restrict__ A,
                                               const u16* __restrict__ Bt,
                                               void* __restrict__ Cout,
                                               int M, int N, int K, int obf16) {
  __shared__ __align__(16) u16 As[128 * 32];
  __shared__ __align__(16) u16 Bs[128 * 32];
  const int t = threadIdx.x;
  const int lane = t & 63, wid = t >> 6;
  const int wm = (wid >> 1) * 64, wn = (wid & 1) * 64;
  const int la = lane & 15, lg = lane >> 4;
  const int m0 = blockIdx.y * 128, n0 = blockIdx.x * 128;

  // staging: wave wid loads chunks {2*wid, 2*wid+1}; chunk c = rows [16c,16c+16)
  const int c0 = wid * 2;
  const int srow = c0 * 16 + (lane >> 2);
  const int scol = (lane & 3) * 8;
  const u16* Ap = A + (size_t)(m0 + srow) * K + scol;
  const u16* Bp = Bt + (size_t)(n0 + srow) * K + scol;
  u16* Ad0 = &As[c0 * 512];
  u16* Ad1 = &As[(c0 + 1) * 512];
  u16* Bd0 = &Bs[c0 * 512];
  u16* Bd1 = &Bs[(c0 + 1) * 512];
  const size_t rstepA = (size_t)16 * K;

  f32x4 acc[4][4] = {};

  for (int k0 = 0; k0 < K; k0 += 32) {
    __syncthreads();
    gll16(Ap + k0, Ad0);
    gll16(Ap + k0 + rstepA, Ad1);
    gll16(Bp + k0, Bd0);
    gll16(Bp + k0 + rstepA, Bd1);
    __syncthreads();   // compiler drains vmcnt before barrier
    bf8 af[4], bfr[4];
#pragma unroll
    for (int i = 0; i < 4; ++i)
      af[i] = asbf8(*(const u16x8*)(&As[(wm + i * 16 + la) * 32 + lg * 8]));
#pragma unroll
    for (int j = 0; j < 4; ++j)
      bfr[j] = asbf8(*(const u16x8*)(&Bs[(wn + j * 16 + la) * 32 + lg * 8]));
    __builtin_amdgcn_s_setprio(1);
#pragma unroll
    for (int i = 0; i < 4; ++i)
#pragma unroll
      for (int j = 0; j < 4; ++j)
        acc[i][j] = __builtin_amdgcn_mfma_f32_16x16x32_bf16(af[i], bfr[j],
                                                            acc[i][j], 0, 0, 0);
    __builtin_amdgcn_s_setprio(0);
  }

#pragma unroll
  for (int i = 0; i < 4; ++i)
#pragma unroll
    for (int j = 0; j < 4; ++j)
#pragma unroll
      for (int r = 0; r < 4; ++r) {
        int row = m0 + wm + i * 16 + lg * 4 + r;
        int col = n0 + wn + j * 16 + la;
        if (obf16) ((u16*)Cout)[(size_t)row * N + col] = f2b(acc[i][j][r]);
        else       ((float*)Cout)[(size_t)row * N + col] = acc[i][j][r];
      }
}

// ---------------- flash attention ----------------
// block = (head h, q-tile of 64). 4 waves x 16 q-rows. KV tiles of 64, causal.
// K/V staged via global_load_lds into linear [64][64] with XOR swizzle
// byte ^= ((row&7)<<4) applied on the (pre-swizzled) global source + reads.

__global__ __launch_bounds__(256) void attn_fwd(const u16* __restrict__ qkv,
                                                const u16* __restrict__ Vt,
                                                u16* __restrict__ aout) {
  const int h  = blockIdx.x;
  const int q0 = (31 - blockIdx.y) * 64;   // heavy (late) q-tiles dispatch first
  const int kh = h >> 2;                    // GROUPS = 4
  __shared__ __align__(16) u16 Ks[64 * 64];   // K[kv][d], swizzled
  __shared__ __align__(16) u16 Vs[64 * 64];   // V^T[d][kv], swizzled
  __shared__ __align__(16) u16 Ps[4 * 16 * 64]; // per-wave P[q][kv], swizzled
  const int t = threadIdx.x, lane = t & 63, w = t >> 6;
  const int la = lane & 15, lg = lane >> 4;

  // swizzled read offsets (bytes->elems), shared by K, V, P reads
  const int koff0 = (((0 * 64 + lg * 16) ^ ((la & 7) << 4)) >> 1);
  const int koff1 = (((1 * 64 + lg * 16) ^ ((la & 7) << 4)) >> 1);

  // staging geometry: wave w loads chunks {2w, 2w+1}; chunk c = rows [8c, 8c+8)
  const int c0 = w * 2;
  const int srow = c0 * 8 + (lane >> 3);
  const int scolE = ((lane & 7) ^ (lane >> 3)) * 8;  // inverse-swizzled src col
  const u16* Kbase = qkv + 2048 + kh * 64;
  const u16* Vbase = Vt + (size_t)kh * 64 * 2048;
  u16* Kd0 = &Ks[c0 * 512]; u16* Kd1 = &Ks[(c0 + 1) * 512];
  u16* Vd0 = &Vs[c0 * 512]; u16* Vd1 = &Vs[(c0 + 1) * 512];

  // Q fragments (A operand), prescaled by 1/8 (exact)
  bf8 aq[2];
  {
    const int qrow = q0 + w * 16 + la;
#pragma unroll
    for (int kk = 0; kk < 2; ++kk) {
      u16x8 v = *(const u16x8*)(qkv + (size_t)qrow * 3072 + h * 64 + kk * 32 + lg * 8);
      u16x8 sv;
#pragma unroll
      for (int e = 0; e < 8; ++e) sv[e] = f2b(b2f(v[e]) * 0.125f);
      aq[kk] = asbf8(sv);
    }
  }

  float m_run[4], l_run[4];
  f32x4 oacc[4] = {};
#pragma unroll
  for (int r = 0; r < 4; ++r) { m_run[r] = -1e30f; l_run[r] = 0.f; }

  for (int j0 = 0; j0 <= q0; j0 += 64) {
    __syncthreads();
    gll16(Kbase + (size_t)(j0 + srow) * 3072 + scolE, Kd0);
    gll16(Kbase + (size_t)(j0 + srow + 8) * 3072 + scolE, Kd1);
    gll16(Vbase + (size_t)srow * 2048 + j0 + scolE, Vd0);
    gll16(Vbase + (size_t)(srow + 8) * 2048 + j0 + scolE, Vd1);
    __syncthreads();

    // S = (Q/8) K^T
    f32x4 sacc[4] = {};
    __builtin_amdgcn_s_setprio(1);
#pragma unroll
    for (int j = 0; j < 4; ++j) {
      const int rb = (j * 16 + la) * 64;
      bf8 bk0 = asbf8(*(const u16x8*)(&Ks[rb + koff0]));
      bf8 bk1 = asbf8(*(const u16x8*)(&Ks[rb + koff1]));
      sacc[j] = __builtin_amdgcn_mfma_f32_16x16x32_bf16(aq[0], bk0, sacc[j], 0, 0, 0);
      sacc[j] = __builtin_amdgcn_mfma_f32_16x16x32_bf16(aq[1], bk1, sacc[j], 0, 0, 0);
    }
    __builtin_amdgcn_s_setprio(0);

    if (j0 == q0) {  // diagonal tile: causal mask
#pragma unroll
      for (int j = 0; j < 4; ++j)
#pragma unroll
        for (int r = 0; r < 4; ++r)
          if (j * 16 + la > w * 16 + lg * 4 + r) sacc[j][r] = -1e30f;
    }

    // online softmax (q-row lives in a 16-lane group: lg fixed, la = kv)
#pragma unroll
    for (int r = 0; r < 4; ++r) {
      float mx = fmaxf(fmaxf(sacc[0][r], sacc[1][r]), fmaxf(sacc[2][r], sacc[3][r]));
      mx = fmaxf(mx, __shfl_xor(mx, 1));
      mx = fmaxf(mx, __shfl_xor(mx, 2));
      mx = fmaxf(mx, __shfl_xor(mx, 4));
      mx = fmaxf(mx, __shfl_xor(mx, 8));
      if (!__all(mx - m_run[r] <= 8.0f)) {   // defer-max (T13, THR=8)
        float m_new = fmaxf(m_run[r], mx);
        float sc = __expf(m_run[r] - m_new);
        m_run[r] = m_new;
        l_run[r] *= sc;
#pragma unroll
        for (int jd = 0; jd < 4; ++jd) oacc[jd][r] *= sc;
      }
      float rs = 0.f;
#pragma unroll
      for (int j = 0; j < 4; ++j) {
        float p = __expf(sacc[j][r] - m_run[r]);
        sacc[j][r] = p;
        rs += p;
      }
      rs += __shfl_xor(rs, 1);
      rs += __shfl_xor(rs, 2);
      rs += __shfl_xor(rs, 4);
      rs += __shfl_xor(rs, 8);
      l_run[r] += rs;
    }

    // P -> LDS (C-frag -> A-frag re-layout), wave-private, swizzled
    {
      u16* Pw = &Ps[w * 1024];
#pragma unroll
      for (int j = 0; j < 4; ++j)
#pragma unroll
        for (int r = 0; r < 4; ++r) {
          const int prow = lg * 4 + r;
          const int pb = ((j * 32 + la * 2) ^ ((prow & 7) << 4)) >> 1;
          Pw[prow * 64 + pb] = f2b(sacc[j][r]);
        }
      bf8 pa0 = asbf8(*(const u16x8*)(&Pw[la * 64 + koff0]));
      bf8 pa1 = asbf8(*(const u16x8*)(&Pw[la * 64 + koff1]));
      __builtin_amdgcn_s_setprio(1);
#pragma unroll
      for (int jd = 0; jd < 4; ++jd) {
        const int rb = (jd * 16 + la) * 64;
        bf8 vb0 = asbf8(*(const u16x8*)(&Vs[rb + koff0]));
        bf8 vb1 = asbf8(*(const u16x8*)(&Vs[rb + koff1]));
        oacc[jd] = __builtin_amdgcn_mfma_f32_16x16x32_bf16(pa0, vb0, oacc[jd], 0, 0, 0);
        oacc[jd] = __builtin_amdgcn_mfma_f32_16x16x32_bf16(pa1, vb1, oacc[jd], 0, 0, 0);
      }
      __builtin_amdgcn_s_setprio(0);
    }
  }

#pragma unroll
  for (int jd = 0; jd < 4; ++jd)
#pragma unroll
    for (int r = 0; r < 4; ++r) {
      int row = q0 + w * 16 + lg * 4 + r;
      int col = h * 64 + jd * 16 + la;
      aout[(size_t)row * 2048 + col] = f2b(oacc[jd][r] / l_run[r]);
    }
}

// ---------------- launch ----------------

extern "C" void kernel_launch(void* const* d_in, const int* in_sizes, int n_in,
                              void* d_out, int out_size, void* d_ws, size_t ws_size,
                              hipStream_t stream) {
  (void)in_sizes; (void)n_in; (void)out_size; (void)ws_size;
  const float* x  = (const float*)d_in[0];
  const float* wq = (const float*)d_in[1];
  const float* wk = (const float*)d_in[2];
  const float* wv = (const float*)d_in[3];
  const float* wo = (const float*)d_in[4];
  const float* cs = (const float*)d_in[5];
  const float* sn = (const float*)d_in[6];
  // d_in[7] = causal mask, implemented analytically

  u16* ws    = (u16*)d_ws;
  u16* xb    = ws;                               // [2048][2048]  (later reused as aout)
  u16* wqkvT = ws + 4194304;                     // [3072][2048]  (later reused for Vt)
  u16* qkv   = ws + 4194304 + 6291456;           // [2048][3072]
  u16* woT   = ws + 4194304 + 6291456 * 2;       // [2048][2048]
  u16* Vt    = wqkvT;                            // [8][64][2048] after G1 is done
  u16* aout  = xb;                               // after G1 is done

  xconv<<<4096, 256, 0, stream>>>(x, xb);
  wtrans<<<dim3(64, 64), 256, 0, stream>>>(wq, wqkvT, 2048, 2048);
  wtrans<<<dim3(16, 64), 256, 0, stream>>>(wk, wqkvT + (size_t)2048 * 2048, 512, 2048);
  wtrans<<<dim3(16, 64), 256, 0, stream>>>(wv, wqkvT + (size_t)2560 * 2048, 512, 2048);
  wtrans<<<dim3(64, 64), 256, 0, stream>>>(wo, woT, 2048, 2048);

  gemm_bt<<<dim3(24, 16), 256, 0, stream>>>(xb, wqkvT, qkv, 2048, 3072, 2048, 1);
  rope_k<<<10240, 256, 0, stream>>>(qkv, cs, sn);
  vtrans<<<4096, 256, 0, stream>>>(qkv, Vt);
  attn_fwd<<<dim3(32, 32), 256, 0, stream>>>(qkv, Vt, aout);
  gemm_bt<<<dim3(16, 16), 256, 0, stream>>>(aout, woT, d_out, 2048, 2048, 2048, 0);
}